// Round 5
// baseline (1037.639 us; speedup 1.0000x reference)
//
#include <hip/hip_runtime.h>
#include <cstdint>
#include <cstddef>

#define NN 50000
#define NE 1600000
#define XD 1025

typedef unsigned short ushortt;
typedef __attribute__((ext_vector_type(8))) short short8;
typedef __attribute__((ext_vector_type(4))) float f32x4;

__device__ __forceinline__ float relu_f(float v) { return v > 0.f ? v : 0.f; }
__device__ __forceinline__ float b2f(ushortt u) { return __uint_as_float(((unsigned)u) << 16); }
__device__ __forceinline__ float blo(unsigned u) { return __uint_as_float(u << 16); }
__device__ __forceinline__ float bhi(unsigned u) { return __uint_as_float(u & 0xffff0000u); }
__device__ __forceinline__ ushortt bf16rn(float f) {
    unsigned u = __float_as_uint(f);
    return (ushortt)((u + 0x7fffu + ((u >> 16) & 1u)) >> 16);
}
__device__ __forceinline__ void load_lds16(const void* g, void* l) {
    __builtin_amdgcn_global_load_lds(
        (const __attribute__((address_space(1))) void*)g,
        (__attribute__((address_space(3))) void*)l, 16, 0, 0);
}

// ================= bf16 MFMA GEMM =================
// A: (M,K) bf16 row-major, lda. Bt: (N,K) bf16 row-major. bias f32 or null.
template <int ACT>
__global__ __launch_bounds__(256) void gemm_mfma(
    const ushortt* __restrict__ A, int lda,
    const ushortt* __restrict__ Bt,
    ushortt* __restrict__ C, int ldc,
    const float* __restrict__ bias,
    int M, int K)
{
    __shared__ ushortt As[128 * 32];
    __shared__ ushortt Bs[128 * 32];
    const int tid = threadIdx.x;
    const int w = tid >> 6, l = tid & 63;
    const int wr = w >> 1, wc = w & 1;
    const int brow = blockIdx.y << 7;
    const int bcol = blockIdx.x << 7;

    f32x4 acc[4][4] = {};

    const int rA0 = wr * 64 + (l & 15);
    const int rB0 = wc * 64 + (l & 15);
    const int kslot = l >> 4;

    for (int k0 = 0; k0 < K; k0 += 32) {
#pragma unroll
        for (int c = 0; c < 2; ++c) {
            int rl = c * 64 + w * 16 + (l >> 2);
            int csel = (l & 3) ^ (rl & 3);
            int gr = brow + rl; if (gr >= M) gr = M - 1;
            load_lds16(A + (size_t)gr * lda + k0 + csel * 8, &As[(c * 64 + w * 16) * 32]);
        }
#pragma unroll
        for (int c = 0; c < 2; ++c) {
            int rl = c * 64 + w * 16 + (l >> 2);
            int csel = (l & 3) ^ (rl & 3);
            load_lds16(Bt + (size_t)(bcol + rl) * K + k0 + csel * 8, &Bs[(c * 64 + w * 16) * 32]);
        }
        __syncthreads();

        short8 af[4], bf[4];
#pragma unroll
        for (int mi = 0; mi < 4; ++mi) {
            int row = rA0 + mi * 16;
            af[mi] = *(const short8*)&As[row * 32 + ((kslot ^ (row & 3)) << 3)];
        }
#pragma unroll
        for (int ni = 0; ni < 4; ++ni) {
            int row = rB0 + ni * 16;
            bf[ni] = *(const short8*)&Bs[row * 32 + ((kslot ^ (row & 3)) << 3)];
        }
#pragma unroll
        for (int mi = 0; mi < 4; ++mi)
#pragma unroll
            for (int ni = 0; ni < 4; ++ni)
                acc[mi][ni] = __builtin_amdgcn_mfma_f32_16x16x32_bf16(af[mi], bf[ni], acc[mi][ni], 0, 0, 0);
        __syncthreads();
    }

    const int cb = bcol + wc * 64 + (l & 15);
    const int rb = brow + wr * 64 + ((l >> 4) << 2);
#pragma unroll
    for (int mi = 0; mi < 4; ++mi) {
#pragma unroll
        for (int ni = 0; ni < 4; ++ni) {
            int col = cb + ni * 16;
            float bv = bias ? bias[col] : 0.f;
#pragma unroll
            for (int r = 0; r < 4; ++r) {
                int row = rb + mi * 16 + r;
                if (row < M) {
                    float v = acc[mi][ni][r] + bv;
                    if (ACT == 1) v = relu_f(v);
                    C[(size_t)row * ldc + col] = bf16rn(v);
                }
            }
        }
    }
}

// ================= fused QK projection + attention + pbar =================
// p: (4*NN,256) bf16 rows n*4+t. ipw16: bf16, rows 0..255 = Wq, 256..511 = Wk.
// pbar[n, h*256+c] = sum_tj asum[n,h,tj] * p[n*4+tj, c],
// asum[n,h,tj] = mean_ti softmax_tj(q_ti . k_tj / 8)
__global__ __launch_bounds__(256) void fused_attn_qk(
    const ushortt* __restrict__ p,
    const ushortt* __restrict__ ipw16,
    const float* __restrict__ ipb,
    ushortt* __restrict__ pbar)
{
    __shared__ __align__(16) ushortt p_s[32 * 256];   // 16B slots xor-swizzled by row&7
    __shared__ __align__(16) ushortt qs[32 * 264];
    __shared__ __align__(16) ushortt ks[32 * 264];
    __shared__ float asum_s[8][4][4];                 // [node][h][tj]

    const int tid = threadIdx.x;
    const int w = tid >> 6, l = tid & 63;
    const int nb = blockIdx.x << 3;
    const size_t r0 = (size_t)nb * 4;

    // ---- stage p (swizzled source slots, linear LDS dest) ----
    {
        const int slot = l & 31;
#pragma unroll
        for (int c = 0; c < 4; ++c) {
            int row = w * 8 + c * 2 + (l >> 5);
            load_lds16(p + (r0 + row) * 256 + ((slot ^ (row & 7)) << 3),
                       &p_s[(w * 8 + c * 2) * 256]);
        }
    }
    __syncthreads();

    const int nq = w << 6;      // this wave's 64-col strip == head w
    // ---- interleaved q,k MFMA: 8 indep B-loads feed 16 MFMAs per iter ----
    f32x4 aq[2][4] = {}, ak[2][4] = {};
    const int ar0 = l & 15, ar1 = ar0 + 16;
#pragma unroll
    for (int kk = 0; kk < 8; ++kk) {
        const int slot = (kk << 2) + (l >> 4);
        short8 a0 = *(const short8*)&p_s[ar0 * 256 + ((slot ^ (ar0 & 7)) << 3)];
        short8 a1 = *(const short8*)&p_s[ar1 * 256 + ((slot ^ (ar1 & 7)) << 3)];
        short8 bq[4], bk[4];
#pragma unroll
        for (int ni = 0; ni < 4; ++ni) {
            int br = nq + (ni << 4) + (l & 15);
            bq[ni] = *(const short8*)&ipw16[(size_t)br * 256 + (kk << 5) + ((l >> 4) << 3)];
            bk[ni] = *(const short8*)&ipw16[(size_t)(256 + br) * 256 + (kk << 5) + ((l >> 4) << 3)];
        }
#pragma unroll
        for (int ni = 0; ni < 4; ++ni) {
            aq[0][ni] = __builtin_amdgcn_mfma_f32_16x16x32_bf16(a0, bq[ni], aq[0][ni], 0, 0, 0);
            aq[1][ni] = __builtin_amdgcn_mfma_f32_16x16x32_bf16(a1, bq[ni], aq[1][ni], 0, 0, 0);
            ak[0][ni] = __builtin_amdgcn_mfma_f32_16x16x32_bf16(a0, bk[ni], ak[0][ni], 0, 0, 0);
            ak[1][ni] = __builtin_amdgcn_mfma_f32_16x16x32_bf16(a1, bk[ni], ak[1][ni], 0, 0, 0);
        }
    }
    // ---- epilogue: q,k (+bias) to LDS ----
#pragma unroll
    for (int mt = 0; mt < 2; ++mt) {
#pragma unroll
        for (int ni = 0; ni < 4; ++ni) {
            int col = nq + (ni << 4) + (l & 15);
            float bq_ = ipb[col], bk_ = ipb[256 + col];
#pragma unroll
            for (int r = 0; r < 4; ++r) {
                int row = (mt << 4) + ((l >> 4) << 2) + r;
                qs[row * 264 + col] = bf16rn(aq[mt][ni][r] + bq_);
                ks[row * 264 + col] = bf16rn(ak[mt][ni][r] + bk_);
            }
        }
    }
    __syncthreads();

    // ---- scores + softmax + asum: thread = (node,h,ti), 128 threads ----
    if (tid < 128) {
        const int node = tid >> 4, h = (tid >> 2) & 3, ti = tid & 3;
        const ushortt* qp = &qs[(node * 4 + ti) * 264 + (h << 6)];
        uint4 qv[8];
#pragma unroll
        for (int sl = 0; sl < 8; ++sl)
            qv[sl] = *(const uint4*)(qp + (((sl + 2 * h) & 7) << 3));   // h-rotated slots
        float s[4];
#pragma unroll
        for (int tj = 0; tj < 4; ++tj) {
            const ushortt* kp = &ks[(node * 4 + tj) * 264 + (h << 6)];
            float a = 0.f;
#pragma unroll
            for (int sl = 0; sl < 8; ++sl) {
                uint4 ka = *(const uint4*)(kp + (((sl + 2 * h) & 7) << 3));
                uint4 qa = qv[sl];
                a += blo(qa.x) * blo(ka.x) + bhi(qa.x) * bhi(ka.x);
                a += blo(qa.y) * blo(ka.y) + bhi(qa.y) * bhi(ka.y);
                a += blo(qa.z) * blo(ka.z) + bhi(qa.z) * bhi(ka.z);
                a += blo(qa.w) * blo(ka.w) + bhi(qa.w) * bhi(ka.w);
            }
            s[tj] = a * 0.125f;
        }
        float m = fmaxf(fmaxf(s[0], s[1]), fmaxf(s[2], s[3]));
        float e0 = expf(s[0] - m), e1 = expf(s[1] - m), e2 = expf(s[2] - m), e3 = expf(s[3] - m);
        float inv = 1.f / (e0 + e1 + e2 + e3);
        float atn[4] = {e0 * inv, e1 * inv, e2 * inv, e3 * inv};
        // asum over ti: 4-lane-group reduce (groups aligned within a wave)
#pragma unroll
        for (int tj = 0; tj < 4; ++tj) {
            float v = atn[tj];
            v += __shfl_xor(v, 1);
            v += __shfl_xor(v, 2);
            if (ti == 0) asum_s[node][h][tj] = 0.25f * v;
        }
    }
    __syncthreads();

    // ---- pbar[n, h*256+c] = sum_tj asum * p_s ----
    {
        const int node = tid >> 5;
        const int c8 = (tid & 31) << 3;
        float f[4][8];
#pragma unroll
        for (int tj = 0; tj < 4; ++tj) {
            int row = node * 4 + tj;
            uint4 u = *(const uint4*)&p_s[row * 256 + (((c8 >> 3) ^ (row & 7)) << 3)];
            f[tj][0] = blo(u.x); f[tj][1] = bhi(u.x); f[tj][2] = blo(u.y); f[tj][3] = bhi(u.y);
            f[tj][4] = blo(u.z); f[tj][5] = bhi(u.z); f[tj][6] = blo(u.w); f[tj][7] = bhi(u.w);
        }
#pragma unroll
        for (int h = 0; h < 4; ++h) {
            float a0 = asum_s[node][h][0], a1 = asum_s[node][h][1];
            float a2 = asum_s[node][h][2], a3 = asum_s[node][h][3];
            ushortt res[8];
#pragma unroll
            for (int i = 0; i < 8; ++i)
                res[i] = bf16rn(a0 * f[0][i] + a1 * f[1][i] + a2 * f[2][i] + a3 * f[3][i]);
            *(uint4*)&pbar[(size_t)(nb + node) * 1024 + h * 256 + c8] = *(uint4*)res;
        }
    }
}

// ================= weight-collapse precompute (tiny, f32) =================
// T = opw^T @ w1  (256x256)
__global__ __launch_bounds__(256) void prep_T(
    const float* __restrict__ opw, const float* __restrict__ w1, float* __restrict__ T)
{
    int d = blockIdx.x, c = threadIdx.x;
    float a = 0.f;
    for (int j = 0; j < 256; ++j)
        a = fmaf(opw[j * 256 + d], w1[j * 256 + c], a);
    T[d * 256 + c] = a;
}

// WbigT[c, h*256+k] = sum_d wv[h*64+d, k] * T[h*64+d, c]   (Bt layout (256,1024))
__global__ __launch_bounds__(256) void prep_wbig(
    const float* __restrict__ wv, const float* __restrict__ T, ushortt* __restrict__ wbigT)
{
    int c = blockIdx.x, kk = threadIdx.x;
#pragma unroll
    for (int h = 0; h < 4; ++h) {
        float a = 0.f;
        for (int d = 0; d < 64; ++d)
            a = fmaf(wv[(h * 64 + d) * 256 + kk], T[(h * 64 + d) * 256 + c], a);
        wbigT[(size_t)c * 1024 + h * 256 + kk] = bf16rn(a);
    }
}

// bbig[c] = sum_j opb[j] w1[j,c] + sum_d bv[d] T[d,c],  bv = ipb[512:]
__global__ __launch_bounds__(256) void prep_bbig(
    const float* __restrict__ opb, const float* __restrict__ w1,
    const float* __restrict__ ipb, const float* __restrict__ T,
    float* __restrict__ bbig)
{
    int c = threadIdx.x;
    float a = 0.f;
    for (int j = 0; j < 256; ++j) a = fmaf(opb[j], w1[j * 256 + c], a);
    for (int d = 0; d < 256; ++d) a = fmaf(ipb[512 + d], T[d * 256 + c], a);
    bbig[c] = a;
}

// ================= conversions =================
__global__ __launch_bounds__(256) void conv_x(
    const float* __restrict__ x, ushortt* __restrict__ ago,
    ushortt* __restrict__ are, ushortt* __restrict__ ame)
{
    long idx = blockIdx.x * 256L + threadIdx.x;
    if (idx >= (long)NN * 128) return;
    int n = (int)(idx >> 7);
    int c8 = ((int)idx & 127) << 3;
    const float* src = x + (size_t)n * XD + c8;
    ushortt* dst;
    if (c8 < 512) dst = ago + (size_t)n * 512 + c8;
    else if (c8 < 768) dst = are + (size_t)n * 256 + (c8 - 512);
    else dst = ame + (size_t)n * 256 + (c8 - 768);
    ushort4 o1, o2;
    o1.x = bf16rn(src[0]); o1.y = bf16rn(src[1]); o1.z = bf16rn(src[2]); o1.w = bf16rn(src[3]);
    o2.x = bf16rn(src[4]); o2.y = bf16rn(src[5]); o2.z = bf16rn(src[6]); o2.w = bf16rn(src[7]);
    *(ushort4*)dst = o1;
    *(ushort4*)(dst + 4) = o2;
}

__global__ __launch_bounds__(256) void convT(
    const float* __restrict__ in, ushortt* __restrict__ out, int R, int C)
{
    int idx = blockIdx.x * 256 + threadIdx.x;
    if (idx >= R * C) return;
    int c = idx / R, r = idx - c * R;
    out[idx] = bf16rn(in[(size_t)r * C + c]);
}

__global__ __launch_bounds__(256) void convF(
    const float* __restrict__ in, ushortt* __restrict__ out, int n)
{
    int idx = blockIdx.x * 256 + threadIdx.x;
    if (idx < n) out[idx] = bf16rn(in[idx]);
}

// ================= gw branch: p row n*4+3 ================
__global__ __launch_bounds__(256) void gw_kernel(
    const float* __restrict__ x, const float* __restrict__ w_gw,
    const float* __restrict__ b_gw, ushortt* __restrict__ p)
{
    long idx = blockIdx.x * 256L + threadIdx.x;
    if (idx >= (long)NN * 64) return;
    int n = (int)(idx >> 6);
    int c = ((int)idx & 63) << 2;
    float g = x[(size_t)n * XD + 1024];
    float4 w4 = *(const float4*)(w_gw + c);
    float4 b4 = *(const float4*)(b_gw + c);
    ushort4 r;
    r.x = bf16rn(relu_f(fmaf(g, w4.x, b4.x)));
    r.y = bf16rn(relu_f(fmaf(g, w4.y, b4.y)));
    r.z = bf16rn(relu_f(fmaf(g, w4.z, b4.z)));
    r.w = bf16rn(relu_f(fmaf(g, w4.w, b4.w)));
    *(ushort4*)(p + (size_t)n * 1024 + 768 + c) = r;
}

// ================= CSR build ================
__global__ __launch_bounds__(256) void deg_int_kernel(
    const int* __restrict__ dst, int* __restrict__ deg, int E)
{
    for (int e = blockIdx.x * 256 + threadIdx.x; e < E; e += gridDim.x * 256)
        atomicAdd(&deg[dst[e]], 1);
}

__global__ __launch_bounds__(256) void dinv_kernel(
    const int* __restrict__ deg, float* __restrict__ dinv, int N)
{
    int n = blockIdx.x * 256 + threadIdx.x;
    if (n < N) dinv[n] = rsqrtf((float)deg[n] + 1.0f);
}

__global__ __launch_bounds__(1024) void scan_kernel(
    const int* __restrict__ deg, int* __restrict__ offs, int N)
{
    __shared__ int wsum[16];
    __shared__ int s_carry;
    const int tid = threadIdx.x;
    const int lane = tid & 63;
    const int w = tid >> 6;
    if (tid == 0) s_carry = 0;
    __syncthreads();
    for (int base = 0; base < N; base += 1024) {
        int i = base + tid;
        int v = (i < N) ? deg[i] : 0;
        int x = v;
#pragma unroll
        for (int d = 1; d < 64; d <<= 1) {
            int t = __shfl_up(x, d);
            if (lane >= d) x += t;
        }
        if (lane == 63) wsum[w] = x;
        __syncthreads();
        if (w == 0 && lane < 16) {
            int y = wsum[lane];
#pragma unroll
            for (int d = 1; d < 16; d <<= 1) {
                int t = __shfl_up(y, d);
                if (lane >= d) y += t;
            }
            wsum[lane] = y;
        }
        __syncthreads();
        int waveoff = (w == 0) ? 0 : wsum[w - 1];
        if (i < N) offs[i] = s_carry + waveoff + x - v;
        __syncthreads();
        if (tid == 0) s_carry += wsum[15];
        __syncthreads();
    }
    if (tid == 0) offs[N] = s_carry;
}

__global__ __launch_bounds__(256) void csr_fill(
    const int* __restrict__ ei, const int* __restrict__ offs,
    int* __restrict__ cursor, int* __restrict__ csr_src,
    float* __restrict__ csr_nrm, const float* __restrict__ dinv, int E)
{
    for (int e = blockIdx.x * 256 + threadIdx.x; e < E; e += gridDim.x * 256) {
        int s = ei[e];
        int d = ei[NE + e];
        int pos = offs[d] + atomicAdd(&cursor[d], 1);
        csr_src[pos] = s;
        csr_nrm[pos] = dinv[s] * dinv[d];
    }
}

// ================= GCN gather ================
template <int F, int ACT, int OUTBF>
__global__ __launch_bounds__(256) void gcn_gather(
    const int* __restrict__ offs, const int* __restrict__ csr_src,
    const float* __restrict__ csr_nrm, const ushortt* __restrict__ hw,
    const float* __restrict__ dinv, const float* __restrict__ bias,
    void* __restrict__ outb, int N)
{
    constexpr int VEC = F / 64;
    const int wid = blockIdx.x * 4 + (threadIdx.x >> 6);
    const int lane = threadIdx.x & 63;
    if (wid >= N) return;
    const int col = lane * VEC;

    float acc[VEC];
    float self = dinv[wid] * dinv[wid];
    if (VEC == 4) {
        ushort4 r = *(const ushort4*)(hw + (size_t)wid * F + col);
        acc[0] = self * b2f(r.x); acc[1] = self * b2f(r.y);
        acc[2] = self * b2f(r.z); acc[3] = self * b2f(r.w);
    } else {
        ushort2 r = *(const ushort2*)(hw + (size_t)wid * F + col);
        acc[0] = self * b2f(r.x); acc[1] = self * b2f(r.y);
    }

    int e = offs[wid];
    const int end = offs[wid + 1];
    for (; e + 1 < end; e += 2) {
        int s0 = csr_src[e], s1 = csr_src[e + 1];
        float n0 = csr_nrm[e], n1 = csr_nrm[e + 1];
        if (VEC == 4) {
            ushort4 r0 = *(const ushort4*)(hw + (size_t)s0 * F + col);
            ushort4 r1 = *(const ushort4*)(hw + (size_t)s1 * F + col);
            acc[0] = fmaf(n0, b2f(r0.x), acc[0]); acc[1] = fmaf(n0, b2f(r0.y), acc[1]);
            acc[2] = fmaf(n0, b2f(r0.z), acc[2]); acc[3] = fmaf(n0, b2f(r0.w), acc[3]);
            acc[0] = fmaf(n1, b2f(r1.x), acc[0]); acc[1] = fmaf(n1, b2f(r1.y), acc[1]);
            acc[2] = fmaf(n1, b2f(r1.z), acc[2]); acc[3] = fmaf(n1, b2f(r1.w), acc[3]);
        } else {
            ushort2 r0 = *(const ushort2*)(hw + (size_t)s0 * F + col);
            ushort2 r1 = *(const ushort2*)(hw + (size_t)s1 * F + col);
            acc[0] = fmaf(n0, b2f(r0.x), acc[0]); acc[1] = fmaf(n0, b2f(r0.y), acc[1]);
            acc[0] = fmaf(n1, b2f(r1.x), acc[0]); acc[1] = fmaf(n1, b2f(r1.y), acc[1]);
        }
    }
    if (e < end) {
        int s0 = csr_src[e];
        float n0 = csr_nrm[e];
        if (VEC == 4) {
            ushort4 r0 = *(const ushort4*)(hw + (size_t)s0 * F + col);
            acc[0] = fmaf(n0, b2f(r0.x), acc[0]); acc[1] = fmaf(n0, b2f(r0.y), acc[1]);
            acc[2] = fmaf(n0, b2f(r0.z), acc[2]); acc[3] = fmaf(n0, b2f(r0.w), acc[3]);
        } else {
            ushort2 r0 = *(const ushort2*)(hw + (size_t)s0 * F + col);
            acc[0] = fmaf(n0, b2f(r0.x), acc[0]); acc[1] = fmaf(n0, b2f(r0.y), acc[1]);
        }
    }

#pragma unroll
    for (int jj = 0; jj < VEC; ++jj) {
        acc[jj] += bias[col + jj];
        if (ACT == 1) acc[jj] = relu_f(acc[jj]);
    }
    if (OUTBF == 1) {
        ushortt* ob = (ushortt*)outb;
#pragma unroll
        for (int jj = 0; jj < VEC; ++jj)
            ob[(size_t)wid * F + col + jj] = bf16rn(acc[jj]);
    } else {
        float* ob = (float*)outb;
#pragma unroll
        for (int jj = 0; jj < VEC; ++jj)
            ob[(size_t)wid * F + col + jj] = acc[jj];
    }
}

// ================= launch ================
extern "C" void kernel_launch(void* const* d_in, const int* in_sizes, int n_in,
                              void* d_out, int out_size, void* d_ws, size_t ws_size,
                              hipStream_t stream)
{
    const float* x    = (const float*)d_in[0];
    const int*   ei   = (const int*)d_in[1];
    const float* w_go = (const float*)d_in[2];
    const float* b_go = (const float*)d_in[3];
    const float* w_re = (const float*)d_in[4];
    const float* b_re = (const float*)d_in[5];
    const float* w_me = (const float*)d_in[6];
    const float* b_me = (const float*)d_in[7];
    const float* w_gw = (const float*)d_in[8];
    const float* b_gw = (const float*)d_in[9];
    const float* ipw  = (const float*)d_in[10];
    const float* ipb  = (const float*)d_in[11];
    const float* opw  = (const float*)d_in[12];
    const float* opb  = (const float*)d_in[13];
    const float* w1   = (const float*)d_in[14];
    const float* b1   = (const float*)d_in[15];
    const float* w2   = (const float*)d_in[16];
    const float* b2   = (const float*)d_in[17];
    float* out = (float*)d_out;
    char* ws   = (char*)d_ws;

    size_t off = 0;
    auto alloc = [&](size_t bytes) { size_t o = off; off += (bytes + 255) & ~(size_t)255; return o; };
    const size_t o_dinv = alloc(NN * 4);
    const size_t o_deg  = alloc(NN * 4);
    const size_t o_offs = alloc((NN + 1) * 4);
    const size_t o_cur  = alloc(NN * 4);
    const size_t o_csrs = alloc((size_t)NE * 4);
    const size_t o_csrn = alloc((size_t)NE * 4);
    const size_t o_wgo  = alloc(256 * 512 * 2);
    const size_t o_wre  = alloc(256 * 256 * 2);
    const size_t o_wme  = alloc(256 * 256 * 2);
    const size_t o_ipw  = alloc(512 * 256 * 2);       // bf16 Wq|Wk only
    const size_t o_T    = alloc(256 * 256 * 4);       // f32
    const size_t o_wbig = alloc(256 * 1024 * 2);      // bf16 Bt (256,1024)
    const size_t o_bbig = alloc(256 * 4);             // f32
    const size_t o_w1t  = alloc(256 * 256 * 2);       // (unused now, kept cheap) -- dropped below
    const size_t o_w2t  = alloc(128 * 256 * 2);
    const size_t o_pbr  = alloc((size_t)4 * NN * 256 * 2);   // p rows n*4+t
    const size_t o_x16  = alloc((size_t)NN * 1024 * 2);      // ago|are|ame
    const size_t o_pbar = alloc((size_t)NN * 1024 * 2);
    const size_t o_hw   = alloc((size_t)NN * 256 * 2);
    const size_t o_h1   = alloc((size_t)NN * 256 * 2);
    const size_t o_hw2  = alloc((size_t)NN * 128 * 2);
    (void)o_w1t;

    float* f_dinv = (float*)(ws + o_dinv);
    int*   i_deg  = (int*)(ws + o_deg);
    int*   i_offs = (int*)(ws + o_offs);
    int*   i_cur  = (int*)(ws + o_cur);
    int*   i_csrs = (int*)(ws + o_csrs);
    float* f_csrn = (float*)(ws + o_csrn);
    float* f_T    = (float*)(ws + o_T);
    float* f_bbig = (float*)(ws + o_bbig);
    ushortt* p    = (ushortt*)(ws + o_pbr);
    ushortt* ago  = (ushortt*)(ws + o_x16);
    ushortt* are  = ago + (size_t)NN * 512;
    ushortt* ame  = ago + (size_t)NN * 768;
    ushortt* pbar = (ushortt*)(ws + o_pbar);
    ushortt* hw   = (ushortt*)(ws + o_hw);
    ushortt* h1   = (ushortt*)(ws + o_h1);
    ushortt* hw2  = (ushortt*)(ws + o_hw2);

    // ---- CSR build ----
    hipMemsetAsync(i_deg, 0, NN * 4, stream);
    hipMemsetAsync(i_cur, 0, NN * 4, stream);
    deg_int_kernel<<<1024, 256, 0, stream>>>(ei + NE, i_deg, NE);
    dinv_kernel<<<(NN + 255) / 256, 256, 0, stream>>>(i_deg, f_dinv, NN);
    scan_kernel<<<1, 1024, 0, stream>>>(i_deg, i_offs, NN);
    csr_fill<<<1024, 256, 0, stream>>>(ei, i_offs, i_cur, i_csrs, f_csrn, f_dinv, NE);

    // ---- weight conversions + collapse precompute ----
    convT<<<(512 * 256 + 255) / 256, 256, 0, stream>>>(w_go, (ushortt*)(ws + o_wgo), 512, 256);
    convT<<<(256 * 256 + 255) / 256, 256, 0, stream>>>(w_re, (ushortt*)(ws + o_wre), 256, 256);
    convT<<<(256 * 256 + 255) / 256, 256, 0, stream>>>(w_me, (ushortt*)(ws + o_wme), 256, 256);
    convT<<<(256 * 128 + 255) / 256, 256, 0, stream>>>(w2,   (ushortt*)(ws + o_w2t), 256, 128);
    convF<<<(512 * 256 + 255) / 256, 256, 0, stream>>>(ipw,  (ushortt*)(ws + o_ipw), 512 * 256);
    prep_T<<<256, 256, 0, stream>>>(opw, w1, f_T);
    prep_wbig<<<256, 256, 0, stream>>>(ipw + 512 * 256, f_T, (ushortt*)(ws + o_wbig));
    prep_bbig<<<1, 256, 0, stream>>>(opb, w1, ipb, f_T, f_bbig);

    // ---- x -> bf16 branch inputs ----
    conv_x<<<((long)NN * 128 + 255) / 256, 256, 0, stream>>>(x, ago, are, ame);

    // ---- branch projections: p rows n*4+t ----
    dim3 gGo(2, (NN + 127) / 128);
    gemm_mfma<1><<<gGo, 256, 0, stream>>>(ago, 512, (ushortt*)(ws + o_wgo), p,       1024, b_go, NN, 512);
    gemm_mfma<1><<<gGo, 256, 0, stream>>>(are, 256, (ushortt*)(ws + o_wre), p + 256, 1024, b_re, NN, 256);
    gemm_mfma<1><<<gGo, 256, 0, stream>>>(ame, 256, (ushortt*)(ws + o_wme), p + 512, 1024, b_me, NN, 256);
    gw_kernel<<<((long)NN * 64 + 255) / 256, 256, 0, stream>>>(x, w_gw, b_gw, p);

    // ---- fused QK + attention + pbar ----
    fused_attn_qk<<<NN / 8, 256, 0, stream>>>(p, (ushortt*)(ws + o_ipw), ipb, pbar);

    // ---- collapsed mean/out_proj/w1: hw = pbar @ Wbig + bbig ----
    dim3 gB(2, (NN + 127) / 128);
    gemm_mfma<0><<<gB, 256, 0, stream>>>(pbar, 1024, (ushortt*)(ws + o_wbig), hw, 256, f_bbig, NN, 1024);

    // ---- GCN layer 1 ----
    gcn_gather<256, 1, 1><<<(NN + 3) / 4, 256, 0, stream>>>(i_offs, i_csrs, f_csrn, hw, f_dinv, b1, h1, NN);

    // ---- GCN layer 2 ----
    dim3 gH2(1, (NN + 127) / 128);
    gemm_mfma<0><<<gH2, 256, 0, stream>>>(h1, 256, (ushortt*)(ws + o_w2t), hw2, 128, nullptr, NN, 256);
    gcn_gather<128, 0, 0><<<(NN + 3) / 4, 256, 0, stream>>>(i_offs, i_csrs, f_csrn, hw2, f_dinv, b2, out, NN);
}

// Round 6
// 950.871 us; speedup vs baseline: 1.0913x; 1.0913x over previous
//
#include <hip/hip_runtime.h>
#include <cstdint>
#include <cstddef>

#define NN 50000
#define NE 1600000
#define XD 1025

typedef unsigned short ushortt;
typedef __attribute__((ext_vector_type(8))) short short8;
typedef __attribute__((ext_vector_type(4))) float f32x4;

__device__ __forceinline__ float relu_f(float v) { return v > 0.f ? v : 0.f; }
__device__ __forceinline__ float b2f(ushortt u) { return __uint_as_float(((unsigned)u) << 16); }
__device__ __forceinline__ float blo(unsigned u) { return __uint_as_float(u << 16); }
__device__ __forceinline__ float bhi(unsigned u) { return __uint_as_float(u & 0xffff0000u); }
__device__ __forceinline__ ushortt bf16rn(float f) {
    unsigned u = __float_as_uint(f);
    return (ushortt)((u + 0x7fffu + ((u >> 16) & 1u)) >> 16);
}
__device__ __forceinline__ void load_lds16(const void* g, void* l) {
    __builtin_amdgcn_global_load_lds(
        (const __attribute__((address_space(1))) void*)g,
        (__attribute__((address_space(3))) void*)l, 16, 0, 0);
}

// ================= bf16 MFMA GEMM =================
template <int ACT>
__global__ __launch_bounds__(256) void gemm_mfma(
    const ushortt* __restrict__ A, int lda,
    const ushortt* __restrict__ Bt,
    ushortt* __restrict__ C, int ldc,
    const float* __restrict__ bias,
    int M, int K)
{
    __shared__ ushortt As[128 * 32];
    __shared__ ushortt Bs[128 * 32];
    const int tid = threadIdx.x;
    const int w = tid >> 6, l = tid & 63;
    const int wr = w >> 1, wc = w & 1;
    const int brow = blockIdx.y << 7;
    const int bcol = blockIdx.x << 7;

    f32x4 acc[4][4] = {};

    const int rA0 = wr * 64 + (l & 15);
    const int rB0 = wc * 64 + (l & 15);
    const int kslot = l >> 4;

    for (int k0 = 0; k0 < K; k0 += 32) {
#pragma unroll
        for (int c = 0; c < 2; ++c) {
            int rl = c * 64 + w * 16 + (l >> 2);
            int csel = (l & 3) ^ (rl & 3);
            int gr = brow + rl; if (gr >= M) gr = M - 1;
            load_lds16(A + (size_t)gr * lda + k0 + csel * 8, &As[(c * 64 + w * 16) * 32]);
        }
#pragma unroll
        for (int c = 0; c < 2; ++c) {
            int rl = c * 64 + w * 16 + (l >> 2);
            int csel = (l & 3) ^ (rl & 3);
            load_lds16(Bt + (size_t)(bcol + rl) * K + k0 + csel * 8, &Bs[(c * 64 + w * 16) * 32]);
        }
        __syncthreads();

        short8 af[4], bf[4];
#pragma unroll
        for (int mi = 0; mi < 4; ++mi) {
            int row = rA0 + mi * 16;
            af[mi] = *(const short8*)&As[row * 32 + ((kslot ^ (row & 3)) << 3)];
        }
#pragma unroll
        for (int ni = 0; ni < 4; ++ni) {
            int row = rB0 + ni * 16;
            bf[ni] = *(const short8*)&Bs[row * 32 + ((kslot ^ (row & 3)) << 3)];
        }
#pragma unroll
        for (int mi = 0; mi < 4; ++mi)
#pragma unroll
            for (int ni = 0; ni < 4; ++ni)
                acc[mi][ni] = __builtin_amdgcn_mfma_f32_16x16x32_bf16(af[mi], bf[ni], acc[mi][ni], 0, 0, 0);
        __syncthreads();
    }

    const int cb = bcol + wc * 64 + (l & 15);
    const int rb = brow + wr * 64 + ((l >> 4) << 2);
#pragma unroll
    for (int mi = 0; mi < 4; ++mi) {
#pragma unroll
        for (int ni = 0; ni < 4; ++ni) {
            int col = cb + ni * 16;
            float bv = bias ? bias[col] : 0.f;
#pragma unroll
            for (int r = 0; r < 4; ++r) {
                int row = rb + mi * 16 + r;
                if (row < M) {
                    float v = acc[mi][ni][r] + bv;
                    if (ACT == 1) v = relu_f(v);
                    C[(size_t)row * ldc + col] = bf16rn(v);
                }
            }
        }
    }
}

// ================= fused QK + MFMA-scores + softmax + pbar (v3) =================
// p: (4*NN,256) bf16 rows n*4+t. ipw16: rows 0..255=Wq, 256..511=Wk (bf16,(512,256)).
// pbar[n, h*256+c] = sum_tj asum[n,h,tj] p[n*4+tj, c]
// Block: 8 nodes, 4 waves; wave w == head w.
// LDS: sbuf 32KB. Phase 1-2: p tile in sbuf[0:8192). Phase 4-5: qk per-head
// regions sbuf[w*4096 .. +4096) (32 rows x [q 64|k 64] cols). Phase 7: p restaged.
__global__ __launch_bounds__(256) void fused_attn_qk(
    const ushortt* __restrict__ p,
    const ushortt* __restrict__ ipw16,
    const float* __restrict__ ipb,
    ushortt* __restrict__ pbar)
{
    __shared__ __align__(16) ushortt sbuf[16384];
    __shared__ float asum_s[8][4][4];   // [node][h][tj]

    const int tid = threadIdx.x;
    const int w = tid >> 6, l = tid & 63;
    const int nb = blockIdx.x << 3;
    const size_t r0 = (size_t)nb * 4;

    // ---- phase 1: stage p (32 rows x 512B, swizzled src, linear LDS) ----
    {
        const int slot = l & 31;
#pragma unroll
        for (int c = 0; c < 4; ++c) {
            int row = w * 8 + c * 2 + (l >> 5);
            load_lds16(p + (r0 + row) * 256 + ((slot ^ (row & 7)) << 3),
                       &sbuf[(w * 8 + c * 2) * 256]);
        }
    }
    __syncthreads();

    const int nq = w << 6;
    // ---- phase 2: q,k projection MFMA (B streamed from L2) ----
    f32x4 aq[2][4] = {}, ak[2][4] = {};
    const int ar0 = l & 15, ar1 = ar0 + 16;
#pragma unroll
    for (int kk = 0; kk < 8; ++kk) {
        const int slot = (kk << 2) + (l >> 4);
        short8 a0 = *(const short8*)&sbuf[ar0 * 256 + ((slot ^ (ar0 & 7)) << 3)];
        short8 a1 = *(const short8*)&sbuf[ar1 * 256 + ((slot ^ (ar1 & 7)) << 3)];
        short8 bq[4], bk[4];
#pragma unroll
        for (int ni = 0; ni < 4; ++ni) {
            int br = nq + (ni << 4) + (l & 15);
            bq[ni] = *(const short8*)&ipw16[(size_t)br * 256 + (kk << 5) + ((l >> 4) << 3)];
            bk[ni] = *(const short8*)&ipw16[(size_t)(256 + br) * 256 + (kk << 5) + ((l >> 4) << 3)];
        }
#pragma unroll
        for (int ni = 0; ni < 4; ++ni) {
            aq[0][ni] = __builtin_amdgcn_mfma_f32_16x16x32_bf16(a0, bq[ni], aq[0][ni], 0, 0, 0);
            aq[1][ni] = __builtin_amdgcn_mfma_f32_16x16x32_bf16(a1, bq[ni], aq[1][ni], 0, 0, 0);
            ak[0][ni] = __builtin_amdgcn_mfma_f32_16x16x32_bf16(a0, bk[ni], ak[0][ni], 0, 0, 0);
            ak[1][ni] = __builtin_amdgcn_mfma_f32_16x16x32_bf16(a1, bk[ni], ak[1][ni], 0, 0, 0);
        }
    }
    __syncthreads();   // all p reads done; qk regions may now overwrite

    // ---- phase 4: write q,k (+bias, bf16) to own head region, swizzled ----
    {
        const int wbase = w << 12;             // w*4096 ushorts
        const int e7 = l & 7;
        const int shalf = (l & 15) >> 3;       // slot half from lane
#pragma unroll
        for (int mt = 0; mt < 2; ++mt) {
#pragma unroll
            for (int ni = 0; ni < 4; ++ni) {
                int colg = nq + (ni << 4) + (l & 15);
                float bq_ = ipb[colg], bk_ = ipb[256 + colg];
                int qslot = (ni << 1) + shalf;
                int kslot_ = 8 + (ni << 1) + shalf;
#pragma unroll
                for (int r = 0; r < 4; ++r) {
                    int row = (mt << 4) + ((l >> 4) << 2) + r;
                    sbuf[wbase + row * 128 + ((qslot ^ (row & 7)) << 3) + e7]  = bf16rn(aq[mt][ni][r] + bq_);
                    sbuf[wbase + row * 128 + ((kslot_ ^ (row & 7)) << 3) + e7] = bf16rn(ak[mt][ni][r] + bk_);
                }
            }
        }
    }

    // ---- phase 5: score MFMA (per wave, own head; diagonal 16x16 tiles) ----
    f32x4 sc[2] = {};
    {
        const int wbase = w << 12;
#pragma unroll
        for (int tile = 0; tile < 2; ++tile) {
            int row = (tile << 4) + (l & 15);
#pragma unroll
            for (int c = 0; c < 2; ++c) {
                int qs_ = ((c << 2) + (l >> 4));
                int ks_ = 8 + (c << 2) + (l >> 4);
                short8 qf = *(const short8*)&sbuf[wbase + row * 128 + ((qs_ ^ (row & 7)) << 3)];
                short8 kf = *(const short8*)&sbuf[wbase + row * 128 + ((ks_ ^ (row & 7)) << 3)];
                sc[tile] = __builtin_amdgcn_mfma_f32_16x16x32_bf16(qf, kf, sc[tile], 0, 0, 0);
            }
        }
    }

    // ---- phase 6: softmax over tj + mean over ti, on diagonal-valid lanes ----
    // valid lane: (l>>4) == ((l&15)>>2). node = tile*4 + (l>>4), tj = l&3, ti = reg r.
    {
        bool valid = (l >> 4) == ((l & 15) >> 2);
#pragma unroll
        for (int tile = 0; tile < 2; ++tile) {
            float a_sum = 0.f;
#pragma unroll
            for (int r = 0; r < 4; ++r) {
                float v = sc[tile][r] * 0.125f;
                float m = fmaxf(v, __shfl_xor(v, 1));
                m = fmaxf(m, __shfl_xor(m, 2));
                float e = __expf(v - m);
                float s = e + __shfl_xor(e, 1);
                s += __shfl_xor(s, 2);
                a_sum += e / s;
            }
            if (valid)
                asum_s[tile * 4 + (l >> 4)][w][l & 3] = 0.25f * a_sum;
        }
    }
    __syncthreads();   // asum visible; all score LDS reads done

    // ---- phase 7: restage p into sbuf[0:8192) ----
    {
        const int slot = l & 31;
#pragma unroll
        for (int c = 0; c < 4; ++c) {
            int row = w * 8 + c * 2 + (l >> 5);
            load_lds16(p + (r0 + row) * 256 + ((slot ^ (row & 7)) << 3),
                       &sbuf[(w * 8 + c * 2) * 256]);
        }
    }
    __syncthreads();

    // ---- phase 8: pbar[n, h*256+c] ----
    {
        const int node = tid >> 5;
        const int c8 = (tid & 31) << 3;
        float f[4][8];
#pragma unroll
        for (int tj = 0; tj < 4; ++tj) {
            int row = node * 4 + tj;
            uint4 u = *(const uint4*)&sbuf[row * 256 + (((c8 >> 3) ^ (row & 7)) << 3)];
            f[tj][0] = blo(u.x); f[tj][1] = bhi(u.x); f[tj][2] = blo(u.y); f[tj][3] = bhi(u.y);
            f[tj][4] = blo(u.z); f[tj][5] = bhi(u.z); f[tj][6] = blo(u.w); f[tj][7] = bhi(u.w);
        }
#pragma unroll
        for (int h = 0; h < 4; ++h) {
            float a0 = asum_s[node][h][0], a1 = asum_s[node][h][1];
            float a2 = asum_s[node][h][2], a3 = asum_s[node][h][3];
            ushortt res[8];
#pragma unroll
            for (int i = 0; i < 8; ++i)
                res[i] = bf16rn(a0 * f[0][i] + a1 * f[1][i] + a2 * f[2][i] + a3 * f[3][i]);
            *(uint4*)&pbar[(size_t)(nb + node) * 1024 + h * 256 + c8] = *(uint4*)res;
        }
    }
}

// ================= weight-collapse precompute =================
__global__ __launch_bounds__(256) void prep_T(
    const float* __restrict__ opw, const float* __restrict__ w1, float* __restrict__ T)
{
    int d = blockIdx.x, c = threadIdx.x;
    float a = 0.f;
    for (int j = 0; j < 256; ++j)
        a = fmaf(opw[j * 256 + d], w1[j * 256 + c], a);
    T[d * 256 + c] = a;
}

__global__ __launch_bounds__(256) void prep_wbig(
    const float* __restrict__ wv, const float* __restrict__ T, ushortt* __restrict__ wbigT)
{
    int c = blockIdx.x, kk = threadIdx.x;
#pragma unroll
    for (int h = 0; h < 4; ++h) {
        float a = 0.f;
        for (int d = 0; d < 64; ++d)
            a = fmaf(wv[(h * 64 + d) * 256 + kk], T[(h * 64 + d) * 256 + c], a);
        wbigT[(size_t)c * 1024 + h * 256 + kk] = bf16rn(a);
    }
}

__global__ __launch_bounds__(256) void prep_bbig(
    const float* __restrict__ opb, const float* __restrict__ w1,
    const float* __restrict__ ipb, const float* __restrict__ T,
    float* __restrict__ bbig)
{
    int c = threadIdx.x;
    float a = 0.f;
    for (int j = 0; j < 256; ++j) a = fmaf(opb[j], w1[j * 256 + c], a);
    for (int d = 0; d < 256; ++d) a = fmaf(ipb[512 + d], T[d * 256 + c], a);
    bbig[c] = a;
}

// ================= conversions =================
__global__ __launch_bounds__(256) void conv_x(
    const float* __restrict__ x, ushortt* __restrict__ ago,
    ushortt* __restrict__ are, ushortt* __restrict__ ame)
{
    long idx = blockIdx.x * 256L + threadIdx.x;
    if (idx >= (long)NN * 128) return;
    int n = (int)(idx >> 7);
    int c8 = ((int)idx & 127) << 3;
    const float* src = x + (size_t)n * XD + c8;
    ushortt* dst;
    if (c8 < 512) dst = ago + (size_t)n * 512 + c8;
    else if (c8 < 768) dst = are + (size_t)n * 256 + (c8 - 512);
    else dst = ame + (size_t)n * 256 + (c8 - 768);
    ushort4 o1, o2;
    o1.x = bf16rn(src[0]); o1.y = bf16rn(src[1]); o1.z = bf16rn(src[2]); o1.w = bf16rn(src[3]);
    o2.x = bf16rn(src[4]); o2.y = bf16rn(src[5]); o2.z = bf16rn(src[6]); o2.w = bf16rn(src[7]);
    *(ushort4*)dst = o1;
    *(ushort4*)(dst + 4) = o2;
}

__global__ __launch_bounds__(256) void convT(
    const float* __restrict__ in, ushortt* __restrict__ out, int R, int C)
{
    int idx = blockIdx.x * 256 + threadIdx.x;
    if (idx >= R * C) return;
    int c = idx / R, r = idx - c * R;
    out[idx] = bf16rn(in[(size_t)r * C + c]);
}

__global__ __launch_bounds__(256) void convF(
    const float* __restrict__ in, ushortt* __restrict__ out, int n)
{
    int idx = blockIdx.x * 256 + threadIdx.x;
    if (idx < n) out[idx] = bf16rn(in[idx]);
}

// ================= gw branch ================
__global__ __launch_bounds__(256) void gw_kernel(
    const float* __restrict__ x, const float* __restrict__ w_gw,
    const float* __restrict__ b_gw, ushortt* __restrict__ p)
{
    long idx = blockIdx.x * 256L + threadIdx.x;
    if (idx >= (long)NN * 64) return;
    int n = (int)(idx >> 6);
    int c = ((int)idx & 63) << 2;
    float g = x[(size_t)n * XD + 1024];
    float4 w4 = *(const float4*)(w_gw + c);
    float4 b4 = *(const float4*)(b_gw + c);
    ushort4 r;
    r.x = bf16rn(relu_f(fmaf(g, w4.x, b4.x)));
    r.y = bf16rn(relu_f(fmaf(g, w4.y, b4.y)));
    r.z = bf16rn(relu_f(fmaf(g, w4.z, b4.z)));
    r.w = bf16rn(relu_f(fmaf(g, w4.w, b4.w)));
    *(ushort4*)(p + (size_t)n * 1024 + 768 + c) = r;
}

// ================= CSR build ================
__global__ __launch_bounds__(256) void deg_int_kernel(
    const int* __restrict__ dst, int* __restrict__ deg, int E)
{
    int e = (blockIdx.x * 256 + threadIdx.x) * 4;
    if (e >= E) return;
    int4 d = *(const int4*)(dst + e);
    atomicAdd(&deg[d.x], 1);
    atomicAdd(&deg[d.y], 1);
    atomicAdd(&deg[d.z], 1);
    atomicAdd(&deg[d.w], 1);
}

__global__ __launch_bounds__(256) void dinv_kernel(
    const int* __restrict__ deg, float* __restrict__ dinv, int N)
{
    int n = blockIdx.x * 256 + threadIdx.x;
    if (n < N) dinv[n] = rsqrtf((float)deg[n] + 1.0f);
}

// multi-block scan: per-block exclusive scan + block totals
__global__ __launch_bounds__(1024) void scan_blk(
    const int* __restrict__ deg, int* __restrict__ offs, int* __restrict__ btot, int N)
{
    __shared__ int wsum[16];
    const int tid = threadIdx.x;
    const int lane = tid & 63;
    const int w = tid >> 6;
    int i = blockIdx.x * 1024 + tid;
    int v = (i < N) ? deg[i] : 0;
    int x = v;
#pragma unroll
    for (int d = 1; d < 64; d <<= 1) {
        int t = __shfl_up(x, d);
        if (lane >= d) x += t;
    }
    if (lane == 63) wsum[w] = x;
    __syncthreads();
    if (w == 0 && lane < 16) {
        int y = wsum[lane];
#pragma unroll
        for (int d = 1; d < 16; d <<= 1) {
            int t = __shfl_up(y, d);
            if (lane >= d) y += t;
        }
        wsum[lane] = y;
    }
    __syncthreads();
    int waveoff = (w == 0) ? 0 : wsum[w - 1];
    if (i < N) offs[i] = waveoff + x - v;
    if (tid == 0) btot[blockIdx.x] = wsum[15];
}

__global__ __launch_bounds__(64) void scan_tot(int* __restrict__ btot, int nb)
{
    int t = threadIdx.x;
    int v = (t < nb) ? btot[t] : 0;
    int x = v;
#pragma unroll
    for (int d = 1; d < 64; d <<= 1) {
        int tt = __shfl_up(x, d);
        if (t >= d) x += tt;
    }
    if (t < nb) btot[t] = x - v;         // exclusive
    if (t == 63) btot[nb] = x;           // grand total
}

__global__ __launch_bounds__(256) void scan_add(
    const int* __restrict__ btot, int* __restrict__ offs, int N, int nb)
{
    int i = blockIdx.x * 256 + threadIdx.x;
    if (i < N) offs[i] += btot[i >> 10];
    else if (i == N) offs[N] = btot[nb];
}

__global__ __launch_bounds__(256) void csr_fill(
    const int* __restrict__ ei, const int* __restrict__ offs,
    int* __restrict__ cursor, int* __restrict__ csr_src,
    float* __restrict__ csr_nrm, const float* __restrict__ dinv, int E)
{
    for (int e = blockIdx.x * 256 + threadIdx.x; e < E; e += gridDim.x * 256) {
        int s = ei[e];
        int d = ei[NE + e];
        int pos = offs[d] + atomicAdd(&cursor[d], 1);
        csr_src[pos] = s;
        csr_nrm[pos] = dinv[s] * dinv[d];
    }
}

// ================= GCN gather F=256 (bf16 in, VEC=4/lane, unroll 4) ================
template <int ACT, int OUTBF>
__global__ __launch_bounds__(256) void gcn_gather256(
    const int* __restrict__ offs, const int* __restrict__ csr_src,
    const float* __restrict__ csr_nrm, const ushortt* __restrict__ hw,
    const float* __restrict__ dinv, const float* __restrict__ bias,
    void* __restrict__ outb, int N)
{
    const int wid = blockIdx.x * 4 + (threadIdx.x >> 6);
    const int lane = threadIdx.x & 63;
    if (wid >= N) return;
    const int col = lane * 4;

    float acc[4];
    {
        float self = dinv[wid] * dinv[wid];
        ushort4 r = *(const ushort4*)(hw + (size_t)wid * 256 + col);
        acc[0] = self * b2f(r.x); acc[1] = self * b2f(r.y);
        acc[2] = self * b2f(r.z); acc[3] = self * b2f(r.w);
    }

    int e = offs[wid];
    const int end = offs[wid + 1];
    for (; e + 3 < end; e += 4) {
        int s0 = csr_src[e], s1 = csr_src[e + 1], s2 = csr_src[e + 2], s3 = csr_src[e + 3];
        float n0 = csr_nrm[e], n1 = csr_nrm[e + 1], n2 = csr_nrm[e + 2], n3 = csr_nrm[e + 3];
        ushort4 r0 = *(const ushort4*)(hw + (size_t)s0 * 256 + col);
        ushort4 r1 = *(const ushort4*)(hw + (size_t)s1 * 256 + col);
        ushort4 r2 = *(const ushort4*)(hw + (size_t)s2 * 256 + col);
        ushort4 r3 = *(const ushort4*)(hw + (size_t)s3 * 256 + col);
        acc[0] = fmaf(n0, b2f(r0.x), acc[0]); acc[1] = fmaf(n0, b2f(r0.y), acc[1]);
        acc[2] = fmaf(n0, b2f(r0.z), acc[2]); acc[3] = fmaf(n0, b2f(r0.w), acc[3]);
        acc[0] = fmaf(n1, b2f(r1.x), acc[0]); acc[1] = fmaf(n1, b2f(r1.y), acc[1]);
        acc[2] = fmaf(n1, b2f(r1.z), acc[2]); acc[3] = fmaf(n1, b2f(r1.w), acc[3]);
        acc[0] = fmaf(n2, b2f(r2.x), acc[0]); acc[1] = fmaf(n2, b2f(r2.y), acc[1]);
        acc[2] = fmaf(n2, b2f(r2.z), acc[2]); acc[3] = fmaf(n2, b2f(r2.w), acc[3]);
        acc[0] = fmaf(n3, b2f(r3.x), acc[0]); acc[1] = fmaf(n3, b2f(r3.y), acc[1]);
        acc[2] = fmaf(n3, b2f(r3.z), acc[2]); acc[3] = fmaf(n3, b2f(r3.w), acc[3]);
    }
    for (; e < end; ++e) {
        int s0 = csr_src[e];
        float n0 = csr_nrm[e];
        ushort4 r0 = *(const ushort4*)(hw + (size_t)s0 * 256 + col);
        acc[0] = fmaf(n0, b2f(r0.x), acc[0]); acc[1] = fmaf(n0, b2f(r0.y), acc[1]);
        acc[2] = fmaf(n0, b2f(r0.z), acc[2]); acc[3] = fmaf(n0, b2f(r0.w), acc[3]);
    }

#pragma unroll
    for (int jj = 0; jj < 4; ++jj) {
        acc[jj] += bias[col + jj];
        if (ACT == 1) acc[jj] = relu_f(acc[jj]);
    }
    if (OUTBF == 1) {
        ushortt* ob = (ushortt*)outb;
        ushort4 r;
        r.x = bf16rn(acc[0]); r.y = bf16rn(acc[1]); r.z = bf16rn(acc[2]); r.w = bf16rn(acc[3]);
        *(ushort4*)(ob + (size_t)wid * 256 + col) = r;
    } else {
        float* ob = (float*)outb;
        float4 r; r.x = acc[0]; r.y = acc[1]; r.z = acc[2]; r.w = acc[3];
        *(float4*)(ob + (size_t)wid * 256 + col) = r;
    }
}

// ================= GCN gather F=128 (2 edge-groups x 32 lanes, f32 out) ================
__global__ __launch_bounds__(256) void gcn_gather128(
    const int* __restrict__ offs, const int* __restrict__ csr_src,
    const float* __restrict__ csr_nrm, const ushortt* __restrict__ hw,
    const float* __restrict__ dinv, const float* __restrict__ bias,
    float* __restrict__ outb, int N)
{
    const int wid = blockIdx.x * 4 + (threadIdx.x >> 6);
    const int lane = threadIdx.x & 63;
    if (wid >= N) return;
    const int g = lane >> 5;
    const int col = (lane & 31) * 4;

    float acc[4] = {0.f, 0.f, 0.f, 0.f};
    if (g == 0) {
        float self = dinv[wid] * dinv[wid];
        ushort4 r = *(const ushort4*)(hw + (size_t)wid * 128 + col);
        acc[0] = self * b2f(r.x); acc[1] = self * b2f(r.y);
        acc[2] = self * b2f(r.z); acc[3] = self * b2f(r.w);
    }

    const int beg = offs[wid], end = offs[wid + 1];
    int e = beg + g;
    for (; e + 2 < end; e += 4) {
        int s0 = csr_src[e], s1 = csr_src[e + 2];
        float n0 = csr_nrm[e], n1 = csr_nrm[e + 2];
        ushort4 r0 = *(const ushort4*)(hw + (size_t)s0 * 128 + col);
        ushort4 r1 = *(const ushort4*)(hw + (size_t)s1 * 128 + col);
        acc[0] = fmaf(n0, b2f(r0.x), acc[0]); acc[1] = fmaf(n0, b2f(r0.y), acc[1]);
        acc[2] = fmaf(n0, b2f(r0.z), acc[2]); acc[3] = fmaf(n0, b2f(r0.w), acc[3]);
        acc[0] = fmaf(n1, b2f(r1.x), acc[0]); acc[1] = fmaf(n1, b2f(r1.y), acc[1]);
        acc[2] = fmaf(n1, b2f(r1.z), acc[2]); acc[3] = fmaf(n1, b2f(r1.w), acc[3]);
    }
    if (e < end) {
        int s0 = csr_src[e];
        float n0 = csr_nrm[e];
        ushort4 r0 = *(const ushort4*)(hw + (size_t)s0 * 128 + col);
        acc[0] = fmaf(n0, b2f(r0.x), acc[0]); acc[1] = fmaf(n0, b2f(r0.y), acc[1]);
        acc[2] = fmaf(n0, b2f(r0.z), acc[2]); acc[3] = fmaf(n0, b2f(r0.w), acc[3]);
    }

#pragma unroll
    for (int jj = 0; jj < 4; ++jj)
        acc[jj] += __shfl_xor(acc[jj], 32);

    if (g == 0) {
        float4 r;
        r.x = acc[0] + bias[col + 0];
        r.y = acc[1] + bias[col + 1];
        r.z = acc[2] + bias[col + 2];
        r.w = acc[3] + bias[col + 3];
        *(float4*)(outb + (size_t)wid * 128 + col) = r;
    }
}

// ================= launch ================
extern "C" void kernel_launch(void* const* d_in, const int* in_sizes, int n_in,
                              void* d_out, int out_size, void* d_ws, size_t ws_size,
                              hipStream_t stream)
{
    const float* x    = (const float*)d_in[0];
    const int*   ei   = (const int*)d_in[1];
    const float* w_go = (const float*)d_in[2];
    const float* b_go = (const float*)d_in[3];
    const float* w_re = (const float*)d_in[4];
    const float* b_re = (const float*)d_in[5];
    const float* w_me = (const float*)d_in[6];
    const float* b_me = (const float*)d_in[7];
    const float* w_gw = (const float*)d_in[8];
    const float* b_gw = (const float*)d_in[9];
    const float* ipw  = (const float*)d_in[10];
    const float* ipb  = (const float*)d_in[11];
    const float* opw  = (const float*)d_in[12];
    const float* opb  = (const float*)d_in[13];
    const float* w1   = (const float*)d_in[14];
    const float* b1   = (const float*)d_in[15];
    const float* w2   = (const float*)d_in[16];
    const float* b2   = (const float*)d_in[17];
    float* out = (float*)d_out;
    char* ws   = (char*)d_ws;

    size_t off = 0;
    auto alloc = [&](size_t bytes) { size_t o = off; off += (bytes + 255) & ~(size_t)255; return o; };
    const size_t o_dinv = alloc(NN * 4);
    const size_t o_deg  = alloc(NN * 4);
    const size_t o_offs = alloc((NN + 1) * 4);
    const size_t o_cur  = alloc(NN * 4);
    const size_t o_btot = alloc(64 * 4);
    const size_t o_csrs = alloc((size_t)NE * 4);
    const size_t o_csrn = alloc((size_t)NE * 4);
    const size_t o_wgo  = alloc(256 * 512 * 2);
    const size_t o_wre  = alloc(256 * 256 * 2);
    const size_t o_wme  = alloc(256 * 256 * 2);
    const size_t o_ipw  = alloc(512 * 256 * 2);       // bf16 Wq|Wk
    const size_t o_T    = alloc(256 * 256 * 4);
    const size_t o_wbig = alloc(256 * 1024 * 2);
    const size_t o_bbig = alloc(256 * 4);
    const size_t o_w2t  = alloc(128 * 256 * 2);
    const size_t o_pbr  = alloc((size_t)4 * NN * 256 * 2);   // p rows n*4+t
    const size_t o_x16  = alloc((size_t)NN * 1024 * 2);      // ago|are|ame
    const size_t o_pbar = alloc((size_t)NN * 1024 * 2);
    const size_t o_hw   = alloc((size_t)NN * 256 * 2);
    const size_t o_h1   = alloc((size_t)NN * 256 * 2);
    const size_t o_hw2  = alloc((size_t)NN * 128 * 2);

    float* f_dinv = (float*)(ws + o_dinv);
    int*   i_deg  = (int*)(ws + o_deg);
    int*   i_offs = (int*)(ws + o_offs);
    int*   i_cur  = (int*)(ws + o_cur);
    int*   i_btot = (int*)(ws + o_btot);
    int*   i_csrs = (int*)(ws + o_csrs);
    float* f_csrn = (float*)(ws + o_csrn);
    float* f_T    = (float*)(ws + o_T);
    float* f_bbig = (float*)(ws + o_bbig);
    ushortt* p    = (ushortt*)(ws + o_pbr);
    ushortt* ago  = (ushortt*)(ws + o_x16);
    ushortt* are  = ago + (size_t)NN * 512;
    ushortt* ame  = ago + (size_t)NN * 768;
    ushortt* pbar = (ushortt*)(ws + o_pbar);
    ushortt* hw   = (ushortt*)(ws + o_hw);
    ushortt* h1   = (ushortt*)(ws + o_h1);
    ushortt* hw2  = (ushortt*)(ws + o_hw2);

    const int NB_SCAN = (NN + 1023) / 1024;   // 49

    // ---- CSR build ----
    hipMemsetAsync(i_deg, 0, NN * 4, stream);
    hipMemsetAsync(i_cur, 0, NN * 4, stream);
    deg_int_kernel<<<(NE / 4 + 255) / 256, 256, 0, stream>>>(ei + NE, i_deg, NE);
    dinv_kernel<<<(NN + 255) / 256, 256, 0, stream>>>(i_deg, f_dinv, NN);
    scan_blk<<<NB_SCAN, 1024, 0, stream>>>(i_deg, i_offs, i_btot, NN);
    scan_tot<<<1, 64, 0, stream>>>(i_btot, NB_SCAN);
    scan_add<<<(NN + 1 + 255) / 256, 256, 0, stream>>>(i_btot, i_offs, NN, NB_SCAN);
    csr_fill<<<1024, 256, 0, stream>>>(ei, i_offs, i_cur, i_csrs, f_csrn, f_dinv, NE);

    // ---- weight conversions + collapse precompute ----
    convT<<<(512 * 256 + 255) / 256, 256, 0, stream>>>(w_go, (ushortt*)(ws + o_wgo), 512, 256);
    convT<<<(256 * 256 + 255) / 256, 256, 0, stream>>>(w_re, (ushortt*)(ws + o_wre), 256, 256);
    convT<<<(256 * 256 + 255) / 256, 256, 0, stream>>>(w_me, (ushortt*)(ws + o_wme), 256, 256);
    convT<<<(256 * 128 + 255) / 256, 256, 0, stream>>>(w2,   (ushortt*)(ws + o_w2t), 256, 128);
    convF<<<(512 * 256 + 255) / 256, 256, 0, stream>>>(ipw,  (ushortt*)(ws + o_ipw), 512 * 256);
    prep_T<<<256, 256, 0, stream>>>(opw, w1, f_T);
    prep_wbig<<<256, 256, 0, stream>>>(ipw + 512 * 256, f_T, (ushortt*)(ws + o_wbig));
    prep_bbig<<<1, 256, 0, stream>>>(opb, w1, ipb, f_T, f_bbig);

    // ---- x -> bf16 branch inputs ----
    conv_x<<<((long)NN * 128 + 255) / 256, 256, 0, stream>>>(x, ago, are, ame);

    // ---- branch projections: p rows n*4+t ----
    dim3 gGo(2, (NN + 127) / 128);
    gemm_mfma<1><<<gGo, 256, 0, stream>>>(ago, 512, (ushortt*)(ws + o_wgo), p,       1024, b_go, NN, 512);
    gemm_mfma<1><<<gGo, 256, 0, stream>>>(are, 256, (ushortt*)(ws + o_wre), p + 256, 1024, b_re, NN, 256);
    gemm_mfma<1><<<gGo, 256, 0, stream>>>(ame, 256, (ushortt*)(ws + o_wme), p + 512, 1024, b_me, NN, 256);
    gw_kernel<<<((long)NN * 64 + 255) / 256, 256, 0, stream>>>(x, w_gw, b_gw, p);

    // ---- fused QK + attention + pbar ----
    fused_attn_qk<<<NN / 8, 256, 0, stream>>>(p, (ushortt*)(ws + o_ipw), ipb, pbar);

    // ---- collapsed mean/out_proj/w1: hw = pbar @ Wbig + bbig ----
    dim3 gB(2, (NN + 127) / 128);
    gemm_mfma<0><<<gB, 256, 0, stream>>>(pbar, 1024, (ushortt*)(ws + o_wbig), hw, 256, f_bbig, NN, 1024);

    // ---- GCN layer 1 ----
    gcn_gather256<1, 1><<<(NN + 3) / 4, 256, 0, stream>>>(i_offs, i_csrs, f_csrn, hw, f_dinv, b1, h1, NN);

    // ---- GCN layer 2 ----
    dim3 gH2(1, (NN + 127) / 128);
    gemm_mfma<0><<<gH2, 256, 0, stream>>>(h1, 256, (ushortt*)(ws + o_w2t), hw2, 128, nullptr, NN, 256);
    gcn_gather128<<<(NN + 3) / 4, 256, 0, stream>>>(i_offs, i_csrs, f_csrn, hw2, f_dinv, b2, out, NN);
}

// Round 7
// 912.814 us; speedup vs baseline: 1.1367x; 1.0417x over previous
//
#include <hip/hip_runtime.h>
#include <cstdint>
#include <cstddef>

#define NN 50000
#define NE 1600000
#define XD 1025

typedef unsigned short ushortt;
typedef __attribute__((ext_vector_type(8))) short short8;
typedef __attribute__((ext_vector_type(4))) float f32x4;

__device__ __forceinline__ float relu_f(float v) { return v > 0.f ? v : 0.f; }
__device__ __forceinline__ float b2f(ushortt u) { return __uint_as_float(((unsigned)u) << 16); }
__device__ __forceinline__ float blo(unsigned u) { return __uint_as_float(u << 16); }
__device__ __forceinline__ float bhi(unsigned u) { return __uint_as_float(u & 0xffff0000u); }
__device__ __forceinline__ ushortt bf16rn(float f) {
    unsigned u = __float_as_uint(f);
    return (ushortt)((u + 0x7fffu + ((u >> 16) & 1u)) >> 16);
}
__device__ __forceinline__ void load_lds16(const void* g, void* l) {
    __builtin_amdgcn_global_load_lds(
        (const __attribute__((address_space(1))) void*)g,
        (__attribute__((address_space(3))) void*)l, 16, 0, 0);
}

// ================= bf16 MFMA GEMM =================
template <int ACT>
__global__ __launch_bounds__(256) void gemm_mfma(
    const ushortt* __restrict__ A, int lda,
    const ushortt* __restrict__ Bt,
    ushortt* __restrict__ C, int ldc,
    const float* __restrict__ bias,
    int M, int K)
{
    __shared__ ushortt As[128 * 32];
    __shared__ ushortt Bs[128 * 32];
    const int tid = threadIdx.x;
    const int w = tid >> 6, l = tid & 63;
    const int wr = w >> 1, wc = w & 1;
    const int brow = blockIdx.y << 7;
    const int bcol = blockIdx.x << 7;

    f32x4 acc[4][4] = {};

    const int rA0 = wr * 64 + (l & 15);
    const int rB0 = wc * 64 + (l & 15);
    const int kslot = l >> 4;

    for (int k0 = 0; k0 < K; k0 += 32) {
#pragma unroll
        for (int c = 0; c < 2; ++c) {
            int rl = c * 64 + w * 16 + (l >> 2);
            int csel = (l & 3) ^ (rl & 3);
            int gr = brow + rl; if (gr >= M) gr = M - 1;
            load_lds16(A + (size_t)gr * lda + k0 + csel * 8, &As[(c * 64 + w * 16) * 32]);
        }
#pragma unroll
        for (int c = 0; c < 2; ++c) {
            int rl = c * 64 + w * 16 + (l >> 2);
            int csel = (l & 3) ^ (rl & 3);
            load_lds16(Bt + (size_t)(bcol + rl) * K + k0 + csel * 8, &Bs[(c * 64 + w * 16) * 32]);
        }
        __syncthreads();

        short8 af[4], bf[4];
#pragma unroll
        for (int mi = 0; mi < 4; ++mi) {
            int row = rA0 + mi * 16;
            af[mi] = *(const short8*)&As[row * 32 + ((kslot ^ (row & 3)) << 3)];
        }
#pragma unroll
        for (int ni = 0; ni < 4; ++ni) {
            int row = rB0 + ni * 16;
            bf[ni] = *(const short8*)&Bs[row * 32 + ((kslot ^ (row & 3)) << 3)];
        }
#pragma unroll
        for (int mi = 0; mi < 4; ++mi)
#pragma unroll
            for (int ni = 0; ni < 4; ++ni)
                acc[mi][ni] = __builtin_amdgcn_mfma_f32_16x16x32_bf16(af[mi], bf[ni], acc[mi][ni], 0, 0, 0);
        __syncthreads();
    }

    const int cb = bcol + wc * 64 + (l & 15);
    const int rb = brow + wr * 64 + ((l >> 4) << 2);
#pragma unroll
    for (int mi = 0; mi < 4; ++mi) {
#pragma unroll
        for (int ni = 0; ni < 4; ++ni) {
            int col = cb + ni * 16;
            float bv = bias ? bias[col] : 0.f;
#pragma unroll
            for (int r = 0; r < 4; ++r) {
                int row = rb + mi * 16 + r;
                if (row < M) {
                    float v = acc[mi][ni][r] + bv;
                    if (ACT == 1) v = relu_f(v);
                    C[(size_t)row * ldc + col] = bf16rn(v);
                }
            }
        }
    }
}

// ================= fused QK + in-register scores + softmax + pbar (v4) =================
// p: (4*NN,256) bf16 rows n*4+t. ipw16: rows 0..255=Wq, 256..511=Wk.
// Key layout fact: QK-projection MFMA acc[mt][ni][r] has
//   row = mt*16 + (l>>4)*4 + r  (r = token of node mt*4+(l>>4))
//   col = w*64 + ni*16 + (l&15)
// so scores s[ti][tj] = sum_cols q[ti]k[tj] reduce entirely in registers +
// a 4-step shfl_xor over the 16-lane column group. No LDS round-trip,
// no restage (p stays live in LDS), 2 barriers total.
__global__ __launch_bounds__(256) void fused_attn_v4(
    const ushortt* __restrict__ p,
    const ushortt* __restrict__ ipw16,
    const float* __restrict__ ipb,
    ushortt* __restrict__ pbar)
{
    __shared__ __align__(16) ushortt p_s[32 * 256];   // 16B slots xor-swizzled by row&7
    __shared__ float asum_s[8][4][4];                 // [node][h][tj]

    const int tid = threadIdx.x;
    const int w = tid >> 6, l = tid & 63;
    const int nb = blockIdx.x << 3;
    const size_t r0 = (size_t)nb * 4;

    // ---- phase 1: stage p (32 rows x 512B, swizzled src, linear LDS) ----
    {
        const int slot = l & 31;
#pragma unroll
        for (int c = 0; c < 4; ++c) {
            int row = w * 8 + c * 2 + (l >> 5);
            load_lds16(p + (r0 + row) * 256 + ((slot ^ (row & 7)) << 3),
                       &p_s[(w * 8 + c * 2) * 256]);
        }
    }
    __syncthreads();

    const int nq = w << 6;
    // ---- phase 2: q,k projection MFMA (B streamed from L2) ----
    f32x4 aq[2][4] = {}, ak[2][4] = {};
    const int ar0 = l & 15, ar1 = ar0 + 16;
#pragma unroll
    for (int kk = 0; kk < 8; ++kk) {
        const int slot = (kk << 2) + (l >> 4);
        short8 a0 = *(const short8*)&p_s[ar0 * 256 + ((slot ^ (ar0 & 7)) << 3)];
        short8 a1 = *(const short8*)&p_s[ar1 * 256 + ((slot ^ (ar1 & 7)) << 3)];
        short8 bq[4], bk[4];
#pragma unroll
        for (int ni = 0; ni < 4; ++ni) {
            int br = nq + (ni << 4) + (l & 15);
            bq[ni] = *(const short8*)&ipw16[(size_t)br * 256 + (kk << 5) + ((l >> 4) << 3)];
            bk[ni] = *(const short8*)&ipw16[(size_t)(256 + br) * 256 + (kk << 5) + ((l >> 4) << 3)];
        }
#pragma unroll
        for (int ni = 0; ni < 4; ++ni) {
            aq[0][ni] = __builtin_amdgcn_mfma_f32_16x16x32_bf16(a0, bq[ni], aq[0][ni], 0, 0, 0);
            aq[1][ni] = __builtin_amdgcn_mfma_f32_16x16x32_bf16(a1, bq[ni], aq[1][ni], 0, 0, 0);
            ak[0][ni] = __builtin_amdgcn_mfma_f32_16x16x32_bf16(a0, bk[ni], ak[0][ni], 0, 0, 0);
            ak[1][ni] = __builtin_amdgcn_mfma_f32_16x16x32_bf16(a1, bk[ni], ak[1][ni], 0, 0, 0);
        }
    }

    // ---- phase 3: in-register scores + softmax + asum ----
    float bqv[4], bkv[4];
#pragma unroll
    for (int ni = 0; ni < 4; ++ni) {
        int col = nq + (ni << 4) + (l & 15);
        bqv[ni] = ipb[col];
        bkv[ni] = ipb[256 + col];
    }
#pragma unroll
    for (int mt = 0; mt < 2; ++mt) {
        float s[4][4] = {};
#pragma unroll
        for (int ni = 0; ni < 4; ++ni) {
            float qv[4], kv[4];
#pragma unroll
            for (int r = 0; r < 4; ++r) {
                qv[r] = aq[mt][ni][r] + bqv[ni];
                kv[r] = ak[mt][ni][r] + bkv[ni];
            }
#pragma unroll
            for (int ti = 0; ti < 4; ++ti)
#pragma unroll
                for (int tj = 0; tj < 4; ++tj)
                    s[ti][tj] = fmaf(qv[ti], kv[tj], s[ti][tj]);
        }
        // reduce over the 16-lane column group
#pragma unroll
        for (int m = 1; m <= 8; m <<= 1)
#pragma unroll
            for (int ti = 0; ti < 4; ++ti)
#pragma unroll
                for (int tj = 0; tj < 4; ++tj)
                    s[ti][tj] += __shfl_xor(s[ti][tj], m);
        // softmax over tj, mean over ti (redundant across the 16 lanes)
        float asum[4] = {};
#pragma unroll
        for (int ti = 0; ti < 4; ++ti) {
            float v0 = s[ti][0] * 0.125f, v1 = s[ti][1] * 0.125f;
            float v2 = s[ti][2] * 0.125f, v3 = s[ti][3] * 0.125f;
            float m4 = fmaxf(fmaxf(v0, v1), fmaxf(v2, v3));
            float e0 = __expf(v0 - m4), e1 = __expf(v1 - m4);
            float e2 = __expf(v2 - m4), e3 = __expf(v3 - m4);
            float inv = 1.f / (e0 + e1 + e2 + e3);
            asum[0] = fmaf(e0, inv, asum[0]);
            asum[1] = fmaf(e1, inv, asum[1]);
            asum[2] = fmaf(e2, inv, asum[2]);
            asum[3] = fmaf(e3, inv, asum[3]);
        }
        if ((l & 15) == 0) {
            int node = mt * 4 + (l >> 4);
#pragma unroll
            for (int tj = 0; tj < 4; ++tj)
                asum_s[node][w][tj] = 0.25f * asum[tj];
        }
    }
    __syncthreads();

    // ---- phase 4: pbar[n, h*256+c] = sum_tj asum[n,h,tj] * p_s[n*4+tj, c] ----
    {
        const int node = tid >> 5;
        const int c8 = (tid & 31) << 3;
        float f[4][8];
#pragma unroll
        for (int tj = 0; tj < 4; ++tj) {
            int row = node * 4 + tj;
            uint4 u = *(const uint4*)&p_s[row * 256 + (((c8 >> 3) ^ (row & 7)) << 3)];
            f[tj][0] = blo(u.x); f[tj][1] = bhi(u.x); f[tj][2] = blo(u.y); f[tj][3] = bhi(u.y);
            f[tj][4] = blo(u.z); f[tj][5] = bhi(u.z); f[tj][6] = blo(u.w); f[tj][7] = bhi(u.w);
        }
#pragma unroll
        for (int h = 0; h < 4; ++h) {
            float a0 = asum_s[node][h][0], a1 = asum_s[node][h][1];
            float a2 = asum_s[node][h][2], a3 = asum_s[node][h][3];
            ushortt res[8];
#pragma unroll
            for (int i = 0; i < 8; ++i)
                res[i] = bf16rn(a0 * f[0][i] + a1 * f[1][i] + a2 * f[2][i] + a3 * f[3][i]);
            *(uint4*)&pbar[(size_t)(nb + node) * 1024 + h * 256 + c8] = *(uint4*)res;
        }
    }
}

// ================= weight-collapse precompute =================
__global__ __launch_bounds__(256) void prep_T(
    const float* __restrict__ opw, const float* __restrict__ w1, float* __restrict__ T)
{
    int d = blockIdx.x, c = threadIdx.x;
    float a = 0.f;
    for (int j = 0; j < 256; ++j)
        a = fmaf(opw[j * 256 + d], w1[j * 256 + c], a);
    T[d * 256 + c] = a;
}

__global__ __launch_bounds__(256) void prep_wbig(
    const float* __restrict__ wv, const float* __restrict__ T, ushortt* __restrict__ wbigT)
{
    int c = blockIdx.x, kk = threadIdx.x;
#pragma unroll
    for (int h = 0; h < 4; ++h) {
        float a = 0.f;
        for (int d = 0; d < 64; ++d)
            a = fmaf(wv[(h * 64 + d) * 256 + kk], T[(h * 64 + d) * 256 + c], a);
        wbigT[(size_t)c * 1024 + h * 256 + kk] = bf16rn(a);
    }
}

__global__ __launch_bounds__(256) void prep_bbig(
    const float* __restrict__ opb, const float* __restrict__ w1,
    const float* __restrict__ ipb, const float* __restrict__ T,
    float* __restrict__ bbig)
{
    int c = threadIdx.x;
    float a = 0.f;
    for (int j = 0; j < 256; ++j) a = fmaf(opb[j], w1[j * 256 + c], a);
    for (int d = 0; d < 256; ++d) a = fmaf(ipb[512 + d], T[d * 256 + c], a);
    bbig[c] = a;
}

// ================= conversions =================
__global__ __launch_bounds__(256) void conv_x(
    const float* __restrict__ x, ushortt* __restrict__ ago,
    ushortt* __restrict__ are, ushortt* __restrict__ ame)
{
    long idx = blockIdx.x * 256L + threadIdx.x;
    if (idx >= (long)NN * 128) return;
    int n = (int)(idx >> 7);
    int c8 = ((int)idx & 127) << 3;
    const float* src = x + (size_t)n * XD + c8;
    ushortt* dst;
    if (c8 < 512) dst = ago + (size_t)n * 512 + c8;
    else if (c8 < 768) dst = are + (size_t)n * 256 + (c8 - 512);
    else dst = ame + (size_t)n * 256 + (c8 - 768);
    ushort4 o1, o2;
    o1.x = bf16rn(src[0]); o1.y = bf16rn(src[1]); o1.z = bf16rn(src[2]); o1.w = bf16rn(src[3]);
    o2.x = bf16rn(src[4]); o2.y = bf16rn(src[5]); o2.z = bf16rn(src[6]); o2.w = bf16rn(src[7]);
    *(ushort4*)dst = o1;
    *(ushort4*)(dst + 4) = o2;
}

__global__ __launch_bounds__(256) void convT(
    const float* __restrict__ in, ushortt* __restrict__ out, int R, int C)
{
    int idx = blockIdx.x * 256 + threadIdx.x;
    if (idx >= R * C) return;
    int c = idx / R, r = idx - c * R;
    out[idx] = bf16rn(in[(size_t)r * C + c]);
}

__global__ __launch_bounds__(256) void convF(
    const float* __restrict__ in, ushortt* __restrict__ out, int n)
{
    int idx = blockIdx.x * 256 + threadIdx.x;
    if (idx < n) out[idx] = bf16rn(in[idx]);
}

// ================= gw branch ================
__global__ __launch_bounds__(256) void gw_kernel(
    const float* __restrict__ x, const float* __restrict__ w_gw,
    const float* __restrict__ b_gw, ushortt* __restrict__ p)
{
    long idx = blockIdx.x * 256L + threadIdx.x;
    if (idx >= (long)NN * 64) return;
    int n = (int)(idx >> 6);
    int c = ((int)idx & 63) << 2;
    float g = x[(size_t)n * XD + 1024];
    float4 w4 = *(const float4*)(w_gw + c);
    float4 b4 = *(const float4*)(b_gw + c);
    ushort4 r;
    r.x = bf16rn(relu_f(fmaf(g, w4.x, b4.x)));
    r.y = bf16rn(relu_f(fmaf(g, w4.y, b4.y)));
    r.z = bf16rn(relu_f(fmaf(g, w4.z, b4.z)));
    r.w = bf16rn(relu_f(fmaf(g, w4.w, b4.w)));
    *(ushort4*)(p + (size_t)n * 1024 + 768 + c) = r;
}

// ================= CSR build ================
__global__ __launch_bounds__(256) void deg_int_kernel(
    const int* __restrict__ dst, int* __restrict__ deg, int E)
{
    int e = (blockIdx.x * 256 + threadIdx.x) * 4;
    if (e >= E) return;
    int4 d = *(const int4*)(dst + e);
    atomicAdd(&deg[d.x], 1);
    atomicAdd(&deg[d.y], 1);
    atomicAdd(&deg[d.z], 1);
    atomicAdd(&deg[d.w], 1);
}

__global__ __launch_bounds__(256) void dinv_kernel(
    const int* __restrict__ deg, float* __restrict__ dinv, int N)
{
    int n = blockIdx.x * 256 + threadIdx.x;
    if (n < N) dinv[n] = rsqrtf((float)deg[n] + 1.0f);
}

__global__ __launch_bounds__(1024) void scan_blk(
    const int* __restrict__ deg, int* __restrict__ offs, int* __restrict__ btot, int N)
{
    __shared__ int wsum[16];
    const int tid = threadIdx.x;
    const int lane = tid & 63;
    const int w = tid >> 6;
    int i = blockIdx.x * 1024 + tid;
    int v = (i < N) ? deg[i] : 0;
    int x = v;
#pragma unroll
    for (int d = 1; d < 64; d <<= 1) {
        int t = __shfl_up(x, d);
        if (lane >= d) x += t;
    }
    if (lane == 63) wsum[w] = x;
    __syncthreads();
    if (w == 0 && lane < 16) {
        int y = wsum[lane];
#pragma unroll
        for (int d = 1; d < 16; d <<= 1) {
            int t = __shfl_up(y, d);
            if (lane >= d) y += t;
        }
        wsum[lane] = y;
    }
    __syncthreads();
    int waveoff = (w == 0) ? 0 : wsum[w - 1];
    if (i < N) offs[i] = waveoff + x - v;
    if (tid == 0) btot[blockIdx.x] = wsum[15];
}

__global__ __launch_bounds__(64) void scan_tot(int* __restrict__ btot, int nb)
{
    int t = threadIdx.x;
    int v = (t < nb) ? btot[t] : 0;
    int x = v;
#pragma unroll
    for (int d = 1; d < 64; d <<= 1) {
        int tt = __shfl_up(x, d);
        if (t >= d) x += tt;
    }
    if (t < nb) btot[t] = x - v;
    if (t == 63) btot[nb] = x;
}

__global__ __launch_bounds__(256) void scan_add(
    const int* __restrict__ btot, int* __restrict__ offs, int N, int nb)
{
    int i = blockIdx.x * 256 + threadIdx.x;
    if (i < N) offs[i] += btot[i >> 10];
    else if (i == N) offs[N] = btot[nb];
}

__global__ __launch_bounds__(256) void csr_fill(
    const int* __restrict__ ei, const int* __restrict__ offs,
    int* __restrict__ cursor, int* __restrict__ csr_src,
    float* __restrict__ csr_nrm, const float* __restrict__ dinv, int E)
{
    for (int e = blockIdx.x * 256 + threadIdx.x; e < E; e += gridDim.x * 256) {
        int s = ei[e];
        int d = ei[NE + e];
        int pos = offs[d] + atomicAdd(&cursor[d], 1);
        csr_src[pos] = s;
        csr_nrm[pos] = dinv[s] * dinv[d];
    }
}

// ================= GCN gather F=256 ================
template <int ACT, int OUTBF>
__global__ __launch_bounds__(256) void gcn_gather256(
    const int* __restrict__ offs, const int* __restrict__ csr_src,
    const float* __restrict__ csr_nrm, const ushortt* __restrict__ hw,
    const float* __restrict__ dinv, const float* __restrict__ bias,
    void* __restrict__ outb, int N)
{
    const int wid = blockIdx.x * 4 + (threadIdx.x >> 6);
    const int lane = threadIdx.x & 63;
    if (wid >= N) return;
    const int col = lane * 4;

    float acc[4];
    {
        float self = dinv[wid] * dinv[wid];
        ushort4 r = *(const ushort4*)(hw + (size_t)wid * 256 + col);
        acc[0] = self * b2f(r.x); acc[1] = self * b2f(r.y);
        acc[2] = self * b2f(r.z); acc[3] = self * b2f(r.w);
    }

    int e = offs[wid];
    const int end = offs[wid + 1];
    for (; e + 3 < end; e += 4) {
        int s0 = csr_src[e], s1 = csr_src[e + 1], s2 = csr_src[e + 2], s3 = csr_src[e + 3];
        float n0 = csr_nrm[e], n1 = csr_nrm[e + 1], n2 = csr_nrm[e + 2], n3 = csr_nrm[e + 3];
        ushort4 r0 = *(const ushort4*)(hw + (size_t)s0 * 256 + col);
        ushort4 r1 = *(const ushort4*)(hw + (size_t)s1 * 256 + col);
        ushort4 r2 = *(const ushort4*)(hw + (size_t)s2 * 256 + col);
        ushort4 r3 = *(const ushort4*)(hw + (size_t)s3 * 256 + col);
        acc[0] = fmaf(n0, b2f(r0.x), acc[0]); acc[1] = fmaf(n0, b2f(r0.y), acc[1]);
        acc[2] = fmaf(n0, b2f(r0.z), acc[2]); acc[3] = fmaf(n0, b2f(r0.w), acc[3]);
        acc[0] = fmaf(n1, b2f(r1.x), acc[0]); acc[1] = fmaf(n1, b2f(r1.y), acc[1]);
        acc[2] = fmaf(n1, b2f(r1.z), acc[2]); acc[3] = fmaf(n1, b2f(r1.w), acc[3]);
        acc[0] = fmaf(n2, b2f(r2.x), acc[0]); acc[1] = fmaf(n2, b2f(r2.y), acc[1]);
        acc[2] = fmaf(n2, b2f(r2.z), acc[2]); acc[3] = fmaf(n2, b2f(r2.w), acc[3]);
        acc[0] = fmaf(n3, b2f(r3.x), acc[0]); acc[1] = fmaf(n3, b2f(r3.y), acc[1]);
        acc[2] = fmaf(n3, b2f(r3.z), acc[2]); acc[3] = fmaf(n3, b2f(r3.w), acc[3]);
    }
    for (; e < end; ++e) {
        int s0 = csr_src[e];
        float n0 = csr_nrm[e];
        ushort4 r0 = *(const ushort4*)(hw + (size_t)s0 * 256 + col);
        acc[0] = fmaf(n0, b2f(r0.x), acc[0]); acc[1] = fmaf(n0, b2f(r0.y), acc[1]);
        acc[2] = fmaf(n0, b2f(r0.z), acc[2]); acc[3] = fmaf(n0, b2f(r0.w), acc[3]);
    }

#pragma unroll
    for (int jj = 0; jj < 4; ++jj) {
        acc[jj] += bias[col + jj];
        if (ACT == 1) acc[jj] = relu_f(acc[jj]);
    }
    if (OUTBF == 1) {
        ushortt* ob = (ushortt*)outb;
        ushort4 r;
        r.x = bf16rn(acc[0]); r.y = bf16rn(acc[1]); r.z = bf16rn(acc[2]); r.w = bf16rn(acc[3]);
        *(ushort4*)(ob + (size_t)wid * 256 + col) = r;
    } else {
        float* ob = (float*)outb;
        float4 r; r.x = acc[0]; r.y = acc[1]; r.z = acc[2]; r.w = acc[3];
        *(float4*)(ob + (size_t)wid * 256 + col) = r;
    }
}

// ================= GCN gather F=128 ================
__global__ __launch_bounds__(256) void gcn_gather128(
    const int* __restrict__ offs, const int* __restrict__ csr_src,
    const float* __restrict__ csr_nrm, const ushortt* __restrict__ hw,
    const float* __restrict__ dinv, const float* __restrict__ bias,
    float* __restrict__ outb, int N)
{
    const int wid = blockIdx.x * 4 + (threadIdx.x >> 6);
    const int lane = threadIdx.x & 63;
    if (wid >= N) return;
    const int g = lane >> 5;
    const int col = (lane & 31) * 4;

    float acc[4] = {0.f, 0.f, 0.f, 0.f};
    if (g == 0) {
        float self = dinv[wid] * dinv[wid];
        ushort4 r = *(const ushort4*)(hw + (size_t)wid * 128 + col);
        acc[0] = self * b2f(r.x); acc[1] = self * b2f(r.y);
        acc[2] = self * b2f(r.z); acc[3] = self * b2f(r.w);
    }

    const int beg = offs[wid], end = offs[wid + 1];
    int e = beg + g;
    for (; e + 2 < end; e += 4) {
        int s0 = csr_src[e], s1 = csr_src[e + 2];
        float n0 = csr_nrm[e], n1 = csr_nrm[e + 2];
        ushort4 r0 = *(const ushort4*)(hw + (size_t)s0 * 128 + col);
        ushort4 r1 = *(const ushort4*)(hw + (size_t)s1 * 128 + col);
        acc[0] = fmaf(n0, b2f(r0.x), acc[0]); acc[1] = fmaf(n0, b2f(r0.y), acc[1]);
        acc[2] = fmaf(n0, b2f(r0.z), acc[2]); acc[3] = fmaf(n0, b2f(r0.w), acc[3]);
        acc[0] = fmaf(n1, b2f(r1.x), acc[0]); acc[1] = fmaf(n1, b2f(r1.y), acc[1]);
        acc[2] = fmaf(n1, b2f(r1.z), acc[2]); acc[3] = fmaf(n1, b2f(r1.w), acc[3]);
    }
    if (e < end) {
        int s0 = csr_src[e];
        float n0 = csr_nrm[e];
        ushort4 r0 = *(const ushort4*)(hw + (size_t)s0 * 128 + col);
        acc[0] = fmaf(n0, b2f(r0.x), acc[0]); acc[1] = fmaf(n0, b2f(r0.y), acc[1]);
        acc[2] = fmaf(n0, b2f(r0.z), acc[2]); acc[3] = fmaf(n0, b2f(r0.w), acc[3]);
    }

#pragma unroll
    for (int jj = 0; jj < 4; ++jj)
        acc[jj] += __shfl_xor(acc[jj], 32);

    if (g == 0) {
        float4 r;
        r.x = acc[0] + bias[col + 0];
        r.y = acc[1] + bias[col + 1];
        r.z = acc[2] + bias[col + 2];
        r.w = acc[3] + bias[col + 3];
        *(float4*)(outb + (size_t)wid * 128 + col) = r;
    }
}

// ================= launch ================
extern "C" void kernel_launch(void* const* d_in, const int* in_sizes, int n_in,
                              void* d_out, int out_size, void* d_ws, size_t ws_size,
                              hipStream_t stream)
{
    const float* x    = (const float*)d_in[0];
    const int*   ei   = (const int*)d_in[1];
    const float* w_go = (const float*)d_in[2];
    const float* b_go = (const float*)d_in[3];
    const float* w_re = (const float*)d_in[4];
    const float* b_re = (const float*)d_in[5];
    const float* w_me = (const float*)d_in[6];
    const float* b_me = (const float*)d_in[7];
    const float* w_gw = (const float*)d_in[8];
    const float* b_gw = (const float*)d_in[9];
    const float* ipw  = (const float*)d_in[10];
    const float* ipb  = (const float*)d_in[11];
    const float* opw  = (const float*)d_in[12];
    const float* opb  = (const float*)d_in[13];
    const float* w1   = (const float*)d_in[14];
    const float* b1   = (const float*)d_in[15];
    const float* w2   = (const float*)d_in[16];
    const float* b2   = (const float*)d_in[17];
    float* out = (float*)d_out;
    char* ws   = (char*)d_ws;

    size_t off = 0;
    auto alloc = [&](size_t bytes) { size_t o = off; off += (bytes + 255) & ~(size_t)255; return o; };
    const size_t o_dinv = alloc(NN * 4);
    const size_t o_deg  = alloc(NN * 4);
    const size_t o_offs = alloc((NN + 1) * 4);
    const size_t o_cur  = alloc(NN * 4);
    const size_t o_btot = alloc(64 * 4);
    const size_t o_csrs = alloc((size_t)NE * 4);
    const size_t o_csrn = alloc((size_t)NE * 4);
    const size_t o_wgo  = alloc(256 * 512 * 2);
    const size_t o_wre  = alloc(256 * 256 * 2);
    const size_t o_wme  = alloc(256 * 256 * 2);
    const size_t o_ipw  = alloc(512 * 256 * 2);
    const size_t o_T    = alloc(256 * 256 * 4);
    const size_t o_wbig = alloc(256 * 1024 * 2);
    const size_t o_bbig = alloc(256 * 4);
    const size_t o_w2t  = alloc(128 * 256 * 2);
    const size_t o_pbr  = alloc((size_t)4 * NN * 256 * 2);
    const size_t o_x16  = alloc((size_t)NN * 1024 * 2);
    const size_t o_pbar = alloc((size_t)NN * 1024 * 2);
    const size_t o_hw   = alloc((size_t)NN * 256 * 2);
    const size_t o_h1   = alloc((size_t)NN * 256 * 2);
    const size_t o_hw2  = alloc((size_t)NN * 128 * 2);

    float* f_dinv = (float*)(ws + o_dinv);
    int*   i_deg  = (int*)(ws + o_deg);
    int*   i_offs = (int*)(ws + o_offs);
    int*   i_cur  = (int*)(ws + o_cur);
    int*   i_btot = (int*)(ws + o_btot);
    int*   i_csrs = (int*)(ws + o_csrs);
    float* f_csrn = (float*)(ws + o_csrn);
    float* f_T    = (float*)(ws + o_T);
    float* f_bbig = (float*)(ws + o_bbig);
    ushortt* p    = (ushortt*)(ws + o_pbr);
    ushortt* ago  = (ushortt*)(ws + o_x16);
    ushortt* are  = ago + (size_t)NN * 512;
    ushortt* ame  = ago + (size_t)NN * 768;
    ushortt* pbar = (ushortt*)(ws + o_pbar);
    ushortt* hw   = (ushortt*)(ws + o_hw);
    ushortt* h1   = (ushortt*)(ws + o_h1);
    ushortt* hw2  = (ushortt*)(ws + o_hw2);

    const int NB_SCAN = (NN + 1023) / 1024;

    // ---- CSR build ----
    hipMemsetAsync(i_deg, 0, NN * 4, stream);
    hipMemsetAsync(i_cur, 0, NN * 4, stream);
    deg_int_kernel<<<(NE / 4 + 255) / 256, 256, 0, stream>>>(ei + NE, i_deg, NE);
    dinv_kernel<<<(NN + 255) / 256, 256, 0, stream>>>(i_deg, f_dinv, NN);
    scan_blk<<<NB_SCAN, 1024, 0, stream>>>(i_deg, i_offs, i_btot, NN);
    scan_tot<<<1, 64, 0, stream>>>(i_btot, NB_SCAN);
    scan_add<<<(NN + 1 + 255) / 256, 256, 0, stream>>>(i_btot, i_offs, NN, NB_SCAN);
    csr_fill<<<1024, 256, 0, stream>>>(ei, i_offs, i_cur, i_csrs, f_csrn, f_dinv, NE);

    // ---- weight conversions + collapse precompute ----
    convT<<<(512 * 256 + 255) / 256, 256, 0, stream>>>(w_go, (ushortt*)(ws + o_wgo), 512, 256);
    convT<<<(256 * 256 + 255) / 256, 256, 0, stream>>>(w_re, (ushortt*)(ws + o_wre), 256, 256);
    convT<<<(256 * 256 + 255) / 256, 256, 0, stream>>>(w_me, (ushortt*)(ws + o_wme), 256, 256);
    convT<<<(256 * 128 + 255) / 256, 256, 0, stream>>>(w2,   (ushortt*)(ws + o_w2t), 256, 128);
    convF<<<(512 * 256 + 255) / 256, 256, 0, stream>>>(ipw,  (ushortt*)(ws + o_ipw), 512 * 256);
    prep_T<<<256, 256, 0, stream>>>(opw, w1, f_T);
    prep_wbig<<<256, 256, 0, stream>>>(ipw + 512 * 256, f_T, (ushortt*)(ws + o_wbig));
    prep_bbig<<<1, 256, 0, stream>>>(opb, w1, ipb, f_T, f_bbig);

    // ---- x -> bf16 branch inputs ----
    conv_x<<<((long)NN * 128 + 255) / 256, 256, 0, stream>>>(x, ago, are, ame);

    // ---- branch projections: p rows n*4+t ----
    dim3 gGo(2, (NN + 127) / 128);
    gemm_mfma<1><<<gGo, 256, 0, stream>>>(ago, 512, (ushortt*)(ws + o_wgo), p,       1024, b_go, NN, 512);
    gemm_mfma<1><<<gGo, 256, 0, stream>>>(are, 256, (ushortt*)(ws + o_wre), p + 256, 1024, b_re, NN, 256);
    gemm_mfma<1><<<gGo, 256, 0, stream>>>(ame, 256, (ushortt*)(ws + o_wme), p + 512, 1024, b_me, NN, 256);
    gw_kernel<<<((long)NN * 64 + 255) / 256, 256, 0, stream>>>(x, w_gw, b_gw, p);

    // ---- fused QK + attention + pbar (v4: in-register scores) ----
    fused_attn_v4<<<NN / 8, 256, 0, stream>>>(p, (ushortt*)(ws + o_ipw), ipb, pbar);

    // ---- collapsed mean/out_proj/w1: hw = pbar @ Wbig + bbig ----
    dim3 gB(2, (NN + 127) / 128);
    gemm_mfma<0><<<gB, 256, 0, stream>>>(pbar, 1024, (ushortt*)(ws + o_wbig), hw, 256, f_bbig, NN, 1024);

    // ---- GCN layer 1 ----
    gcn_gather256<1, 1><<<(NN + 3) / 4, 256, 0, stream>>>(i_offs, i_csrs, f_csrn, hw, f_dinv, b1, h1, NN);

    // ---- GCN layer 2 ----
    dim3 gH2(1, (NN + 127) / 128);
    gemm_mfma<0><<<gH2, 256, 0, stream>>>(h1, 256, (ushortt*)(ws + o_w2t), hw2, 128, nullptr, NN, 256);
    gcn_gather128<<<(NN + 3) / 4, 256, 0, stream>>>(i_offs, i_csrs, f_csrn, hw2, f_dinv, b2, out, NN);
}